// Round 8
// baseline (105.192 us; speedup 1.0000x reference)
//
#include <hip/hip_runtime.h>
#include <math.h>

#define BATCH 64
#define SEQ   2048
#define HID   1024
#define CHUNKS 16
#define ROWS_PER_BLOCK (SEQ / CHUNKS)            // 128
#define NWAVES 4
#define ROWS_PER_WAVE (ROWS_PER_BLOCK / NWAVES)  // 32
#define PART_STRIDE 1028

typedef float f32x4 __attribute__((ext_vector_type(4)));
typedef float f32x2 __attribute__((ext_vector_type(2)));

// VOP3P packed fp32: one instruction, two f32 FMAs per lane (proven +2% r7).
static __device__ __forceinline__ f32x2 pk_fma(f32x2 a, f32x2 b, f32x2 c) {
    f32x2 d;
    asm("v_pk_fma_f32 %0, %1, %2, %3" : "=v"(d) : "v"(a), "v"(b), "v"(c));
    return d;
}
static __device__ __forceinline__ f32x2 pk_mul(f32x2 a, f32x2 b) {
    f32x2 d;
    asm("v_pk_mul_f32 %0, %1, %2" : "=v"(d) : "v"(a), "v"(b));
    return d;
}
static __device__ __forceinline__ f32x2 pk_add(f32x2 a, f32x2 b) {
    f32x2 d;
    asm("v_pk_add_f32 %0, %1, %2" : "=v"(d) : "v"(a), "v"(b));
    return d;
}
static __device__ __forceinline__ f32x2 lo2(f32x4 v) { return f32x2{v.x, v.y}; }
static __device__ __forceinline__ f32x2 hi2(f32x4 v) { return f32x2{v.z, v.w}; }

// Pass 1: fused scores + online-softmax context accumulation, single read of enc.
// Depth-2 register pipeline (proven), packed-fp32 math, deferred-max.
// NEW r8: (a) interleaved chunk->row mapping -- each wave's 32-row window is
// strided across the whole batch so every block sees a uniform L3/HBM source
// mix (anti-straggler); (b) plain loads (no NT hint) to maximize Infinity
// Cache retention across graph replays (round-3 counters showed ~50% of enc
// is served from L3: FETCH_SIZE 265 MB of 512 MB logical).
__global__ __launch_bounds__(256, 4) void attn_pass1(
    const float* __restrict__ dec, const float* __restrict__ enc,
    float* __restrict__ scores, float* __restrict__ partials)
{
    const int b     = blockIdx.x / CHUNKS;
    const int chunk = blockIdx.x % CHUNKS;
    const int tid   = threadIdx.x;
    const int wave  = tid >> 6;
    const int lane  = tid & 63;

    // decoder state resident in registers as 8 f32x2 pairs
    const f32x4* decv = reinterpret_cast<const f32x4*>(dec + b * HID);
    f32x2 sv2[8];
#pragma unroll
    for (int p = 0; p < 4; ++p) {
        f32x4 s = decv[p * 64 + lane];
        sv2[2 * p]     = lo2(s);
        sv2[2 * p + 1] = hi2(s);
    }

    float m = -1e30f, l = 0.0f;
    f32x2 c2[8];
#pragma unroll
    for (int q = 0; q < 8; ++q) c2[q] = f32x2{0.f, 0.f};

    float sreg = 0.0f;   // lane r accumulates row r's score (r < 32)

    // interleaved assignment: 64 windows of 32 rows; this wave takes window
    // (chunk + 16*wave), so one block's 4 windows span the whole batch.
    const int row0 = (chunk + CHUNKS * wave) * ROWS_PER_WAVE;
    const f32x4* rowp = reinterpret_cast<const f32x4*>(enc + (size_t)b * SEQ * HID)
                        + (size_t)row0 * (HID / 4) + lane;

    f32x4 eA[4], eB[4];
#pragma unroll
    for (int p = 0; p < 4; ++p) eA[p] = rowp[p * 64];

    auto process = [&](const f32x4 (&e)[4], int r) {
        // dot: 8 pk_fma, two independent chains
        f32x2 dd0 = pk_mul(lo2(e[0]), sv2[0]);
        f32x2 dd1 = pk_mul(hi2(e[0]), sv2[1]);
#pragma unroll
        for (int p = 1; p < 4; ++p) {
            dd0 = pk_fma(lo2(e[p]), sv2[2 * p],     dd0);
            dd1 = pk_fma(hi2(e[p]), sv2[2 * p + 1], dd1);
        }
        f32x2 dd = pk_add(dd0, dd1);
        float dot = dd.x + dd.y;
#pragma unroll
        for (int off = 32; off > 0; off >>= 1) dot += __shfl_xor(dot, off, 64);

        sreg = (lane == r) ? dot : sreg;    // cndmask, no store

        if (dot <= m) {              // wave-uniform branch; common path
            const float pw = __expf(dot - m);
            l += pw;
            const f32x2 pwv = {pw, pw};
#pragma unroll
            for (int p = 0; p < 4; ++p) {
                c2[2 * p]     = pk_fma(pwv, lo2(e[p]), c2[2 * p]);
                c2[2 * p + 1] = pk_fma(pwv, hi2(e[p]), c2[2 * p + 1]);
            }
        } else {                     // rare (~log S): rescale, pw == 1
            const float sc = __expf(m - dot);   // first row: exp(-huge) = 0
            l = l * sc + 1.0f;
            const f32x2 scv = {sc, sc};
#pragma unroll
            for (int p = 0; p < 4; ++p) {
                c2[2 * p]     = pk_fma(scv, c2[2 * p],     lo2(e[p]));
                c2[2 * p + 1] = pk_fma(scv, c2[2 * p + 1], hi2(e[p]));
            }
            m = dot;
        }
    };

    for (int r = 0; r < ROWS_PER_WAVE; r += 2) {
        const f32x4* rp1 = rowp + (size_t)(r + 1) * (HID / 4);
#pragma unroll
        for (int p = 0; p < 4; ++p) eB[p] = rp1[p * 64];

        process(eA, r);

        if (r + 2 < ROWS_PER_WAVE) {
            const f32x4* rp2 = rowp + (size_t)(r + 2) * (HID / 4);
#pragma unroll
            for (int p = 0; p < 4; ++p) eA[p] = rp2[p * 64];
        }

        process(eB, r + 1);
    }

    // one coalesced score store per wave (lane r holds row r of this window)
    if (lane < ROWS_PER_WAVE) scores[b * SEQ + row0 + lane] = sreg;

    // merge the 4 waves' (m,l,c) in LDS, one partial record per block
    __shared__ float lm[NWAVES], ll[NWAVES];
    __shared__ float lc[NWAVES][HID];
    f32x4* lcw = reinterpret_cast<f32x4*>(lc[wave]);
#pragma unroll
    for (int p = 0; p < 4; ++p)
        lcw[p * 64 + lane] = f32x4{c2[2 * p].x, c2[2 * p].y,
                                   c2[2 * p + 1].x, c2[2 * p + 1].y};
    if (lane == 0) { lm[wave] = m; ll[wave] = l; }
    __syncthreads();

    const float M = fmaxf(fmaxf(lm[0], lm[1]), fmaxf(lm[2], lm[3]));
    float w[NWAVES];
    float L = 0.f;
#pragma unroll
    for (int k = 0; k < NWAVES; ++k) { w[k] = __expf(lm[k] - M); L += ll[k] * w[k]; }

    f32x4 acc = f32x4{0.f, 0.f, 0.f, 0.f};
#pragma unroll
    for (int k = 0; k < NWAVES; ++k) {
        f32x4 v = reinterpret_cast<const f32x4*>(lc[k])[tid];
        acc += v * w[k];
    }
    float* rec = partials + (size_t)blockIdx.x * PART_STRIDE;
    reinterpret_cast<f32x4*>(rec)[tid] = acc;
    if (tid == 0) { rec[HID] = M; rec[HID + 1] = L; }
}

// Pass 2: per (batch, half), merge 16 chunk partials, write context + attn.
__global__ __launch_bounds__(256) void attn_pass2(
    const float* __restrict__ scores, const float* __restrict__ partials,
    float* __restrict__ out_ctx, float* __restrict__ out_attn)
{
    const int b    = blockIdx.x >> 1;
    const int half = blockIdx.x & 1;
    const int t    = threadIdx.x;

    float mk[CHUNKS], lk[CHUNKS];
    float M = -1e30f;
#pragma unroll
    for (int k = 0; k < CHUNKS; ++k) {
        const float* rec = partials + (size_t)(b * CHUNKS + k) * PART_STRIDE;
        mk[k] = rec[HID];
        lk[k] = rec[HID + 1];
        M = fmaxf(M, mk[k]);
    }
    float L = 0.f;
    float wk[CHUNKS];
#pragma unroll
    for (int k = 0; k < CHUNKS; ++k) { wk[k] = __expf(mk[k] - M); L += lk[k] * wk[k]; }
    const float invL = 1.0f / L;

    const int slot = half * 128 + (t & 127);
    if (t < 128) {
        f32x4 acc = f32x4{0.f, 0.f, 0.f, 0.f};
#pragma unroll
        for (int k = 0; k < CHUNKS; ++k) {
            const f32x4* rec4 =
                reinterpret_cast<const f32x4*>(partials + (size_t)(b * CHUNKS + k) * PART_STRIDE);
            acc += rec4[slot] * wk[k];
        }
        acc *= invL;
        reinterpret_cast<f32x4*>(out_ctx + b * HID)[slot] = acc;
    }

    for (int i = half * (SEQ / 2) + t; i < (half + 1) * (SEQ / 2); i += 256) {
        out_attn[b * SEQ + i] = __expf(scores[b * SEQ + i] - M) * invL;
    }
}

extern "C" void kernel_launch(void* const* d_in, const int* in_sizes, int n_in,
                              void* d_out, int out_size, void* d_ws, size_t ws_size,
                              hipStream_t stream) {
    const float* dec = (const float*)d_in[0];   // [64, 1024]
    const float* enc = (const float*)d_in[1];   // [64, 2048, 1024]
    float* out = (float*)d_out;                 // context [64,1024] then attn [64,2048]

    float* scores   = (float*)d_ws;
    float* partials = scores + BATCH * SEQ;

    attn_pass1<<<BATCH * CHUNKS, 256, 0, stream>>>(dec, enc, scores, partials);
    attn_pass2<<<BATCH * 2, 256, 0, stream>>>(scores, partials, out, out + BATCH * HID);
}

// Round 9
// 98.348 us; speedup vs baseline: 1.0696x; 1.0696x over previous
//
#include <hip/hip_runtime.h>
#include <math.h>

#define BATCH 64
#define SEQ   2048
#define HID   1024
#define CHUNKS 16
#define ROWS_PER_BLOCK (SEQ / CHUNKS)            // 128
#define NWAVES 4
#define ROWS_PER_WAVE (ROWS_PER_BLOCK / NWAVES)  // 32
#define PART_STRIDE 1028

typedef float f32x4 __attribute__((ext_vector_type(4)));
typedef float f32x2 __attribute__((ext_vector_type(2)));

// VOP3P packed fp32: one instruction, two f32 FMAs per lane (proven +2% r7).
static __device__ __forceinline__ f32x2 pk_fma(f32x2 a, f32x2 b, f32x2 c) {
    f32x2 d;
    asm("v_pk_fma_f32 %0, %1, %2, %3" : "=v"(d) : "v"(a), "v"(b), "v"(c));
    return d;
}
static __device__ __forceinline__ f32x2 pk_mul(f32x2 a, f32x2 b) {
    f32x2 d;
    asm("v_pk_mul_f32 %0, %1, %2" : "=v"(d) : "v"(a), "v"(b));
    return d;
}
static __device__ __forceinline__ f32x2 pk_add(f32x2 a, f32x2 b) {
    f32x2 d;
    asm("v_pk_add_f32 %0, %1, %2" : "=v"(d) : "v"(a), "v"(b));
    return d;
}
static __device__ __forceinline__ f32x2 lo2(f32x4 v) { return f32x2{v.x, v.y}; }
static __device__ __forceinline__ f32x2 hi2(f32x4 v) { return f32x2{v.z, v.w}; }

// Pass 1: fused scores + online-softmax context accumulation, single read of enc.
// EXACT round-7 structure (best: 98.5 us). Depth-2 register pipeline,
// contiguous per-wave windows, nontemporal loads, packed-fp32 math,
// deferred-max, register score accumulation.
// Proven-dead ends: depth>=3 (null), split-dot (null), fused merge tail
// (allocator collapses pipeline, VGPR 100->52), interleaved windows / plain
// loads (-7%: per-block contiguity + NT is load-bearing).
__global__ __launch_bounds__(256, 4) void attn_pass1(
    const float* __restrict__ dec, const float* __restrict__ enc,
    float* __restrict__ scores, float* __restrict__ partials)
{
    const int b     = blockIdx.x / CHUNKS;
    const int chunk = blockIdx.x % CHUNKS;
    const int tid   = threadIdx.x;
    const int wave  = tid >> 6;
    const int lane  = tid & 63;

    // decoder state resident in registers as 8 f32x2 pairs
    const f32x4* decv = reinterpret_cast<const f32x4*>(dec + b * HID);
    f32x2 sv2[8];
#pragma unroll
    for (int p = 0; p < 4; ++p) {
        f32x4 s = decv[p * 64 + lane];
        sv2[2 * p]     = lo2(s);
        sv2[2 * p + 1] = hi2(s);
    }

    float m = -1e30f, l = 0.0f;
    f32x2 c2[8];
#pragma unroll
    for (int q = 0; q < 8; ++q) c2[q] = f32x2{0.f, 0.f};

    float sreg = 0.0f;   // lane r accumulates row r's score (r < 32)

    const int row0 = chunk * ROWS_PER_BLOCK + wave * ROWS_PER_WAVE;
    const f32x4* rowp = reinterpret_cast<const f32x4*>(enc + (size_t)b * SEQ * HID)
                        + (size_t)row0 * (HID / 4) + lane;

    f32x4 eA[4], eB[4];
#pragma unroll
    for (int p = 0; p < 4; ++p) eA[p] = __builtin_nontemporal_load(rowp + p * 64);

    auto process = [&](const f32x4 (&e)[4], int r) {
        // dot: 8 pk_fma, two independent chains
        f32x2 dd0 = pk_mul(lo2(e[0]), sv2[0]);
        f32x2 dd1 = pk_mul(hi2(e[0]), sv2[1]);
#pragma unroll
        for (int p = 1; p < 4; ++p) {
            dd0 = pk_fma(lo2(e[p]), sv2[2 * p],     dd0);
            dd1 = pk_fma(hi2(e[p]), sv2[2 * p + 1], dd1);
        }
        f32x2 dd = pk_add(dd0, dd1);
        float dot = dd.x + dd.y;
#pragma unroll
        for (int off = 32; off > 0; off >>= 1) dot += __shfl_xor(dot, off, 64);

        sreg = (lane == r) ? dot : sreg;    // cndmask, no store

        if (dot <= m) {              // wave-uniform branch; common path
            const float pw = __expf(dot - m);
            l += pw;
            const f32x2 pwv = {pw, pw};
#pragma unroll
            for (int p = 0; p < 4; ++p) {
                c2[2 * p]     = pk_fma(pwv, lo2(e[p]), c2[2 * p]);
                c2[2 * p + 1] = pk_fma(pwv, hi2(e[p]), c2[2 * p + 1]);
            }
        } else {                     // rare (~log S): rescale, pw == 1
            const float sc = __expf(m - dot);   // first row: exp(-huge) = 0
            l = l * sc + 1.0f;
            const f32x2 scv = {sc, sc};
#pragma unroll
            for (int p = 0; p < 4; ++p) {
                c2[2 * p]     = pk_fma(scv, c2[2 * p],     lo2(e[p]));
                c2[2 * p + 1] = pk_fma(scv, c2[2 * p + 1], hi2(e[p]));
            }
            m = dot;
        }
    };

    for (int r = 0; r < ROWS_PER_WAVE; r += 2) {
        const f32x4* rp1 = rowp + (size_t)(r + 1) * (HID / 4);
#pragma unroll
        for (int p = 0; p < 4; ++p) eB[p] = __builtin_nontemporal_load(rp1 + p * 64);

        process(eA, r);

        if (r + 2 < ROWS_PER_WAVE) {
            const f32x4* rp2 = rowp + (size_t)(r + 2) * (HID / 4);
#pragma unroll
            for (int p = 0; p < 4; ++p) eA[p] = __builtin_nontemporal_load(rp2 + p * 64);
        }

        process(eB, r + 1);
    }

    // one coalesced score store per wave (lane r holds row r)
    if (lane < ROWS_PER_WAVE) scores[b * SEQ + row0 + lane] = sreg;

    // merge the 4 waves' (m,l,c) in LDS, one partial record per block
    __shared__ float lm[NWAVES], ll[NWAVES];
    __shared__ float lc[NWAVES][HID];
    f32x4* lcw = reinterpret_cast<f32x4*>(lc[wave]);
#pragma unroll
    for (int p = 0; p < 4; ++p)
        lcw[p * 64 + lane] = f32x4{c2[2 * p].x, c2[2 * p].y,
                                   c2[2 * p + 1].x, c2[2 * p + 1].y};
    if (lane == 0) { lm[wave] = m; ll[wave] = l; }
    __syncthreads();

    const float M = fmaxf(fmaxf(lm[0], lm[1]), fmaxf(lm[2], lm[3]));
    float w[NWAVES];
    float L = 0.f;
#pragma unroll
    for (int k = 0; k < NWAVES; ++k) { w[k] = __expf(lm[k] - M); L += ll[k] * w[k]; }

    f32x4 acc = f32x4{0.f, 0.f, 0.f, 0.f};
#pragma unroll
    for (int k = 0; k < NWAVES; ++k) {
        f32x4 v = reinterpret_cast<const f32x4*>(lc[k])[tid];
        acc += v * w[k];
    }
    float* rec = partials + (size_t)blockIdx.x * PART_STRIDE;
    reinterpret_cast<f32x4*>(rec)[tid] = acc;
    if (tid == 0) { rec[HID] = M; rec[HID + 1] = L; }
}

// Pass 2: per (batch, half), merge 16 chunk partials, write context + attn.
__global__ __launch_bounds__(256) void attn_pass2(
    const float* __restrict__ scores, const float* __restrict__ partials,
    float* __restrict__ out_ctx, float* __restrict__ out_attn)
{
    const int b    = blockIdx.x >> 1;
    const int half = blockIdx.x & 1;
    const int t    = threadIdx.x;

    float mk[CHUNKS], lk[CHUNKS];
    float M = -1e30f;
#pragma unroll
    for (int k = 0; k < CHUNKS; ++k) {
        const float* rec = partials + (size_t)(b * CHUNKS + k) * PART_STRIDE;
        mk[k] = rec[HID];
        lk[k] = rec[HID + 1];
        M = fmaxf(M, mk[k]);
    }
    float L = 0.f;
    float wk[CHUNKS];
#pragma unroll
    for (int k = 0; k < CHUNKS; ++k) { wk[k] = __expf(mk[k] - M); L += lk[k] * wk[k]; }
    const float invL = 1.0f / L;

    const int slot = half * 128 + (t & 127);
    if (t < 128) {
        f32x4 acc = f32x4{0.f, 0.f, 0.f, 0.f};
#pragma unroll
        for (int k = 0; k < CHUNKS; ++k) {
            const f32x4* rec4 =
                reinterpret_cast<const f32x4*>(partials + (size_t)(b * CHUNKS + k) * PART_STRIDE);
            acc += rec4[slot] * wk[k];
        }
        acc *= invL;
        reinterpret_cast<f32x4*>(out_ctx + b * HID)[slot] = acc;
    }

    for (int i = half * (SEQ / 2) + t; i < (half + 1) * (SEQ / 2); i += 256) {
        out_attn[b * SEQ + i] = __expf(scores[b * SEQ + i] - M) * invL;
    }
}

extern "C" void kernel_launch(void* const* d_in, const int* in_sizes, int n_in,
                              void* d_out, int out_size, void* d_ws, size_t ws_size,
                              hipStream_t stream) {
    const float* dec = (const float*)d_in[0];   // [64, 1024]
    const float* enc = (const float*)d_in[1];   // [64, 2048, 1024]
    float* out = (float*)d_out;                 // context [64,1024] then attn [64,2048]

    float* scores   = (float*)d_ws;
    float* partials = scores + BATCH * SEQ;

    attn_pass1<<<BATCH * CHUNKS, 256, 0, stream>>>(dec, enc, scores, partials);
    attn_pass2<<<BATCH * 2, 256, 0, stream>>>(scores, partials, out, out + BATCH * HID);
}